// Round 4
// baseline (63.682 us; speedup 1.0000x reference)
//
#include <hip/hip_runtime.h>

// GaussianMask: K[b,c,k,h,w] = exp(-(Xnbr - Xctr)^2 / 2), bw=1
// X: (4,3,512,512) fp32. Out: (4,3,24,512,512) fp32. Zero padding, center tap skipped.
// Write-BW-bound: 302 MB out vs 12.6 MB in.
// R4: 4 output rows per thread -> 8x8 register window shared across rows,
//     aligned f32x4 window loads (6 vec loads/quad vs 40 scalar), 96 NT stores/thread.

#define HH 512
#define WW 512
#define NPLANES 12   // B*C = 4*3
#define NK 24
#define HW (HH * WW)

typedef float f32x4 __attribute__((ext_vector_type(4)));

extern "C" __device__ float __builtin_amdgcn_exp2f(float);

__global__ __launch_bounds__(256) void gauss_mask_kernel(
    const float* __restrict__ X, float* __restrict__ out)
{
    // one thread handles a 4(h) x 4(w) output patch, for all 24 k's
    const int tid = blockIdx.x * blockDim.x + threadIdx.x;
    // per plane: 128 row-groups * 128 quads = 16384 threads
    const int p   = tid >> 14;
    const int rem = tid & 16383;
    const int h0  = (rem >> 7) << 2;   // row-group start (wave-uniform)
    const int w0  = (rem & 127) << 2;  // starting col (lane-consecutive -> coalesced)

    const float* Xp = X + (size_t)p * HW;

    // 8x8 window covering rows h0-2..h0+5, cols w0-2..w0+5 (zero-filled OOB)
    const bool wl = (w0 > 0);
    const bool wr = (w0 < WW - 4);
    const int  aL = wl ? w0 - 4 : 0;        // clamped aligned left quad
    const int  aR = wr ? w0 + 4 : WW - 4;   // clamped aligned right quad

    float win[8][8];
    #pragma unroll
    for (int r = 0; r < 8; ++r) {
        const int hh = h0 + r - 2;
        if (hh >= 0 && hh < HH) {           // wave-uniform branch
            const float* rp = Xp + (size_t)hh * WW;
            const f32x4 qL = *reinterpret_cast<const f32x4*>(rp + aL);
            const f32x4 qC = *reinterpret_cast<const f32x4*>(rp + w0);
            const f32x4 qR = *reinterpret_cast<const f32x4*>(rp + aR);
            win[r][0] = wl ? qL[2] : 0.0f;
            win[r][1] = wl ? qL[3] : 0.0f;
            win[r][2] = qC[0];
            win[r][3] = qC[1];
            win[r][4] = qC[2];
            win[r][5] = qC[3];
            win[r][6] = wr ? qR[0] : 0.0f;
            win[r][7] = wr ? qR[1] : 0.0f;
        } else {
            #pragma unroll
            for (int j = 0; j < 8; ++j) win[r][j] = 0.0f;
        }
    }

    // exp(-d^2 * 0.5) = exp2(d^2 * (-0.5 * log2(e)))
    const float c = -0.5f * 1.44269504088896340736f;

    float* outp = out + (size_t)p * NK * HW + (size_t)h0 * WW + w0;

    #pragma unroll
    for (int k = 0; k < NK; ++k) {
        const int idx = (k < 12) ? k : k + 1;   // skip center tap (2,2)
        const int dr = idx / 5;
        const int dc = idx % 5;
        float* kp = outp + (size_t)k * HW;
        #pragma unroll
        for (int hr = 0; hr < 4; ++hr) {
            f32x4 v;
            #pragma unroll
            for (int i = 0; i < 4; ++i) {
                const float d = win[hr + dr][dc + i] - win[hr + 2][2 + i];
                v[i] = __builtin_amdgcn_exp2f(d * d * c);
            }
            __builtin_nontemporal_store(v, reinterpret_cast<f32x4*>(kp + (size_t)hr * WW));
        }
    }
}

extern "C" void kernel_launch(void* const* d_in, const int* in_sizes, int n_in,
                              void* d_out, int out_size, void* d_ws, size_t ws_size,
                              hipStream_t stream) {
    const float* X = (const float*)d_in[0];
    float* out = (float*)d_out;

    // 12 planes * 16384 threads = 196608 threads
    const int total = NPLANES * (HH / 4) * (WW / 4);
    const int block = 256;
    const int grid = total / block;  // 768
    gauss_mask_kernel<<<grid, block, 0, stream>>>(X, out);
}

// Round 5
// 53.842 us; speedup vs baseline: 1.1828x; 1.1828x over previous
//
#include <hip/hip_runtime.h>

// GaussianMask: K[b,c,k,h,w] = exp(-(Xnbr - Xctr)^2 / 2), bw=1
// X: (4,3,512,512) fp32. Out: (4,3,24,512,512) fp32. Zero padding, center skipped.
// Write-BW-bound: 302 MB out vs 12.6 MB in.
// R5: k = blockIdx.y (compile-time dr,dc via switch). Each wave stores into ONE
//     k-plane; grid x-major order writes the output plane-by-plane sequentially
//     (fill-kernel-like store stream) instead of 24 interleaved 1MB-apart streams.

#define HH 512
#define WW 512
#define NPLANES 12   // B*C
#define NK 24
#define HW (HH * WW)

typedef float f32x4 __attribute__((ext_vector_type(4)));

extern "C" __device__ float __builtin_amdgcn_exp2f(float);

template <int DR, int DC>
__device__ __forceinline__ void do_case(const float* __restrict__ Xp,
                                        float* __restrict__ kp,
                                        int h, int w0)
{
    const float c = -0.5f * 1.44269504088896340736f;  // -0.5*log2(e)
    const float* ctr_row = Xp + (size_t)h * WW;
    const f32x4 xc = *reinterpret_cast<const f32x4*>(ctr_row + w0);

    const int hh = h + DR - 2;
    f32x4 nb;
    if (hh >= 0 && hh < HH) {                    // wave-uniform (64 lanes share h)
        const float* nr = Xp + (size_t)hh * WW;
        if constexpr (DC == 2) {
            nb = *reinterpret_cast<const f32x4*>(nr + w0);
        } else if constexpr (DC < 2) {
            const f32x4 qC = *reinterpret_cast<const f32x4*>(nr + w0);
            const f32x4 qA = *reinterpret_cast<const f32x4*>(nr + (w0 > 0 ? w0 - 4 : 0));
            constexpr int off = DC - 2;          // -2 or -1
            #pragma unroll
            for (int i = 0; i < 4; ++i) {
                if constexpr (off + 100) {}      // keep i compile-time
                float v;
                if (off + i < 0) {               // compile-time per i
                    v = (w0 > 0) ? qA[4 + off + i] : 0.0f;
                } else {
                    v = qC[off + i];
                }
                nb[i] = v;
            }
        } else {                                 // DC > 2
            const f32x4 qC = *reinterpret_cast<const f32x4*>(nr + w0);
            const f32x4 qB = *reinterpret_cast<const f32x4*>(nr + (w0 < WW - 4 ? w0 + 4 : WW - 4));
            constexpr int off = DC - 2;          // 1 or 2
            #pragma unroll
            for (int i = 0; i < 4; ++i) {
                float v;
                if (off + i > 3) {               // compile-time per i
                    v = (w0 < WW - 4) ? qB[off + i - 4] : 0.0f;
                } else {
                    v = qC[off + i];
                }
                nb[i] = v;
            }
        }
    } else {
        #pragma unroll
        for (int i = 0; i < 4; ++i) nb[i] = 0.0f;   // zero padding row
    }

    f32x4 v;
    #pragma unroll
    for (int i = 0; i < 4; ++i) {
        const float d = nb[i] - xc[i];
        v[i] = __builtin_amdgcn_exp2f(d * d * c);
    }
    __builtin_nontemporal_store(v, reinterpret_cast<f32x4*>(kp + (size_t)h * WW + w0));
}

__global__ __launch_bounds__(512) void gauss_mask_kernel(
    const float* __restrict__ X, float* __restrict__ out)
{
    // blockIdx.x covers (p,h,w0) quads; blockIdx.y = k (compile-time dr,dc)
    const int idx = blockIdx.x * 512 + threadIdx.x;   // [0, 786432)
    const int p   = idx >> 16;            // 65536 quads per plane
    const int rem = idx & 65535;
    const int h   = rem >> 7;
    const int w0  = (rem & 127) << 2;
    const int k   = blockIdx.y;

    const float* Xp = X + (size_t)p * HW;
    float* kp = out + ((size_t)p * NK + k) * HW;

    switch (k) {
        case  0: do_case<0, 0>(Xp, kp, h, w0); break;
        case  1: do_case<0, 1>(Xp, kp, h, w0); break;
        case  2: do_case<0, 2>(Xp, kp, h, w0); break;
        case  3: do_case<0, 3>(Xp, kp, h, w0); break;
        case  4: do_case<0, 4>(Xp, kp, h, w0); break;
        case  5: do_case<1, 0>(Xp, kp, h, w0); break;
        case  6: do_case<1, 1>(Xp, kp, h, w0); break;
        case  7: do_case<1, 2>(Xp, kp, h, w0); break;
        case  8: do_case<1, 3>(Xp, kp, h, w0); break;
        case  9: do_case<1, 4>(Xp, kp, h, w0); break;
        case 10: do_case<2, 0>(Xp, kp, h, w0); break;
        case 11: do_case<2, 1>(Xp, kp, h, w0); break;
        case 12: do_case<2, 3>(Xp, kp, h, w0); break;
        case 13: do_case<2, 4>(Xp, kp, h, w0); break;
        case 14: do_case<3, 0>(Xp, kp, h, w0); break;
        case 15: do_case<3, 1>(Xp, kp, h, w0); break;
        case 16: do_case<3, 2>(Xp, kp, h, w0); break;
        case 17: do_case<3, 3>(Xp, kp, h, w0); break;
        case 18: do_case<3, 4>(Xp, kp, h, w0); break;
        case 19: do_case<4, 0>(Xp, kp, h, w0); break;
        case 20: do_case<4, 1>(Xp, kp, h, w0); break;
        case 21: do_case<4, 2>(Xp, kp, h, w0); break;
        case 22: do_case<4, 3>(Xp, kp, h, w0); break;
        case 23: do_case<4, 4>(Xp, kp, h, w0); break;
    }
}

extern "C" void kernel_launch(void* const* d_in, const int* in_sizes, int n_in,
                              void* d_out, int out_size, void* d_ws, size_t ws_size,
                              hipStream_t stream) {
    const float* X = (const float*)d_in[0];
    float* out = (float*)d_out;

    // per k: 12 planes * 512 * 128 quads = 786432 threads / 512 = 1536 blocks
    dim3 grid(1536, NK);
    gauss_mask_kernel<<<grid, 512, 0, stream>>>(X, out);
}